// Round 15
// baseline (232.909 us; speedup 1.0000x reference)
//
#include <hip/hip_runtime.h>
#include <hip/hip_bf16.h>

typedef unsigned int uint;
typedef unsigned short ushort;

#define N_NODES 50000
#define N_EDGES 800000
#define FDIM 128
#define HID 64
#define NPERM 128
#define HLLM 64
#define DUMMY 50000                // identity row index

#define BSHIFT 8
#define BNODES 256                 // nodes per bucket
#define NBUCK 196                  // ceil(50000/256)
#define CAPB 6144                  // fixed ebuf capacity/bucket (mean 4096, 32 sigma)
#define SCAT_BLOCKS 256
#define EDGES_PER_BLK 3125         // 800000/256 exactly
#define PACKMH_BLOCKS 12500
#define MH2_BLOCKS 6250            // 8 nodes/block (2 per wave)
#define AGG2_BLOCKS 6250
#define HLL_BLOCKS 3125            // 16 nodes/block
#define SLICE_CAP 8448
#define CONV_BLOCKS 782            // ceil(50000/64)

__device__ __forceinline__ uint pk_min_u16(uint a, uint b) {
    uint d;
    asm("v_pk_min_u16 %0, %1, %2" : "=v"(d) : "v"(a), "v"(b));
    return d;
}

// ========== mh: 2 nodes/wave (lanes 0-31 / 32-63), uint2/lane ==========
// csr uint4 prefetch: next iteration's indices load overlaps current row gathers.

__device__ __forceinline__ void mh_body(int node, uint c2, const int2* __restrict__ off2,
                                        const ushort* __restrict__ csr,
                                        const uint* __restrict__ mh_in,
                                        uint* __restrict__ out_p, float* __restrict__ out_f) {
    int2 se = off2[node];
    uint mnA = 0xFFFFFFFFu, mnB = 0xFFFFFFFFu, mnC = 0xFFFFFFFFu, mnD = 0xFFFFFFFFu;
    int p = se.x;
    uint4 c4 = *(const uint4*)(csr + p);
    for (; p < se.y; ) {
        int pn = p + 8;
        uint4 c4n = *(const uint4*)(csr + pn);   // 16B over-read at end is in-allocation
        uint j0 = c4.x & 0xFFFFu, j1 = c4.x >> 16;
        uint j2 = c4.y & 0xFFFFu, j3 = c4.y >> 16;
        uint j4 = c4.z & 0xFFFFu, j5 = c4.z >> 16;
        uint j6 = c4.w & 0xFFFFu, j7 = c4.w >> 16;
        uint2 a0 = *(const uint2*)(mh_in + j0 * 64u + 2u * c2);
        uint2 a1 = *(const uint2*)(mh_in + j1 * 64u + 2u * c2);
        uint2 a2 = *(const uint2*)(mh_in + j2 * 64u + 2u * c2);
        uint2 a3 = *(const uint2*)(mh_in + j3 * 64u + 2u * c2);
        uint2 a4 = *(const uint2*)(mh_in + j4 * 64u + 2u * c2);
        uint2 a5 = *(const uint2*)(mh_in + j5 * 64u + 2u * c2);
        uint2 a6 = *(const uint2*)(mh_in + j6 * 64u + 2u * c2);
        uint2 a7 = *(const uint2*)(mh_in + j7 * 64u + 2u * c2);
        mnA = pk_min_u16(mnA, a0.x); mnB = pk_min_u16(mnB, a0.y);
        mnC = pk_min_u16(mnC, a1.x); mnD = pk_min_u16(mnD, a1.y);
        mnA = pk_min_u16(mnA, a2.x); mnB = pk_min_u16(mnB, a2.y);
        mnC = pk_min_u16(mnC, a3.x); mnD = pk_min_u16(mnD, a3.y);
        mnA = pk_min_u16(mnA, a4.x); mnB = pk_min_u16(mnB, a4.y);
        mnC = pk_min_u16(mnC, a5.x); mnD = pk_min_u16(mnD, a5.y);
        mnA = pk_min_u16(mnA, a6.x); mnB = pk_min_u16(mnB, a6.y);
        mnC = pk_min_u16(mnC, a7.x); mnD = pk_min_u16(mnD, a7.y);
        c4 = c4n; p = pn;
    }
    uint m0 = pk_min_u16(mnA, mnC);
    uint m1 = pk_min_u16(mnB, mnD);
    if (out_p) {
        uint2 w = {m0, m1};
        *(uint2*)(out_p + (size_t)node * 64 + 2u * c2) = w;
    } else {
        float4 w;
        w.x = __uint_as_float((m0 & 0xFFFFu) << 16);
        w.y = __uint_as_float(m0 & 0xFFFF0000u);
        w.z = __uint_as_float((m1 & 0xFFFFu) << 16);
        w.w = __uint_as_float(m1 & 0xFFFF0000u);
        *(float4*)(out_f + (size_t)node * NPERM + 4u * c2) = w;
    }
}

// ========== hll: 16 lanes/node, uint/lane, csr prefetch ==========

__device__ __forceinline__ void hll_body(int node, uint q, const int2* __restrict__ off2,
                                         const ushort* __restrict__ csr,
                                         const uint* __restrict__ hll_in,
                                         uint* __restrict__ out_p, float* __restrict__ out_f,
                                         float* __restrict__ cards, int kcol) {
    int2 se = off2[node];
    uint m0 = 0, m1 = 0, m2 = 0, m3 = 0;
#define HLL_ACC(vv) do { uint _v = (vv); \
        m0 = max(m0, _v & 0xFFu); m1 = max(m1, (_v >> 8) & 0xFFu); \
        m2 = max(m2, (_v >> 16) & 0xFFu); m3 = max(m3, _v >> 24); } while (0)
    int p = se.x;
    uint4 c4 = *(const uint4*)(csr + p);
    for (; p < se.y; ) {
        int pn = p + 8;
        uint4 c4n = *(const uint4*)(csr + pn);
        uint j0 = c4.x & 0xFFFFu, j1 = c4.x >> 16;
        uint j2 = c4.y & 0xFFFFu, j3 = c4.y >> 16;
        uint j4 = c4.z & 0xFFFFu, j5 = c4.z >> 16;
        uint j6 = c4.w & 0xFFFFu, j7 = c4.w >> 16;
        uint a0 = hll_in[j0 * 16u + q];
        uint a1 = hll_in[j1 * 16u + q];
        uint a2 = hll_in[j2 * 16u + q];
        uint a3 = hll_in[j3 * 16u + q];
        uint a4 = hll_in[j4 * 16u + q];
        uint a5 = hll_in[j5 * 16u + q];
        uint a6 = hll_in[j6 * 16u + q];
        uint a7 = hll_in[j7 * 16u + q];
        HLL_ACC(a0); HLL_ACC(a1); HLL_ACC(a2); HLL_ACC(a3);
        HLL_ACC(a4); HLL_ACC(a5); HLL_ACC(a6); HLL_ACC(a7);
        c4 = c4n; p = pn;
    }
#undef HLL_ACC
    if (out_p) out_p[(size_t)node * 16 + q] = m0 | (m1 << 8) | (m2 << 16) | (m3 << 24);
    if (out_f) {
        float4 w = {(float)m0, (float)m1, (float)m2, (float)m3};
        *(float4*)(out_f + (size_t)node * HLLM + 4 * q) = w;
    }
    float v = exp2f(-(float)m0) + exp2f(-(float)m1) + exp2f(-(float)m2) + exp2f(-(float)m3);
    v += __shfl_xor(v, 1); v += __shfl_xor(v, 2);
    v += __shfl_xor(v, 4); v += __shfl_xor(v, 8);
    if (q == 0) {
        const float alphamm = (float)(0.7213 / (1.0 + 1.079 / 64.0) * 64.0 * 64.0);
        cards[(size_t)node * 2 + kcol] = alphamm / v;
    }
}

// ========== agg: 2 nodes/wave, uint/lane (2 channels), csr prefetch ==========

__device__ __forceinline__ void agg_body(int node, uint c2, const int2* __restrict__ off2,
                                         const ushort* __restrict__ csr,
                                         const uint* __restrict__ hWs32,
                                         const float* __restrict__ dis,
                                         const float* __restrict__ b,
                                         const float* __restrict__ h_in,
                                         float* __restrict__ h_out) {
    int2 se = off2[node];
    float ax0 = 0.f, ay0 = 0.f, ax1 = 0.f, ay1 = 0.f;
    int p = se.x;
    uint4 c4 = *(const uint4*)(csr + p);
    for (; p < se.y; ) {
        int pn = p + 8;
        uint4 c4n = *(const uint4*)(csr + pn);
        uint j0 = c4.x & 0xFFFFu, j1 = c4.x >> 16;
        uint j2 = c4.y & 0xFFFFu, j3 = c4.y >> 16;
        uint j4 = c4.z & 0xFFFFu, j5 = c4.z >> 16;
        uint j6 = c4.w & 0xFFFFu, j7 = c4.w >> 16;
        uint a0 = hWs32[j0 * 32u + c2];
        uint a1 = hWs32[j1 * 32u + c2];
        uint a2 = hWs32[j2 * 32u + c2];
        uint a3 = hWs32[j3 * 32u + c2];
        uint a4 = hWs32[j4 * 32u + c2];
        uint a5 = hWs32[j5 * 32u + c2];
        uint a6 = hWs32[j6 * 32u + c2];
        uint a7 = hWs32[j7 * 32u + c2];
        ax0 += __uint_as_float(a0 << 16) + __uint_as_float(a1 << 16)
             + __uint_as_float(a2 << 16) + __uint_as_float(a3 << 16);
        ay0 += __uint_as_float(a0 & 0xFFFF0000u) + __uint_as_float(a1 & 0xFFFF0000u)
             + __uint_as_float(a2 & 0xFFFF0000u) + __uint_as_float(a3 & 0xFFFF0000u);
        ax1 += __uint_as_float(a4 << 16) + __uint_as_float(a5 << 16)
             + __uint_as_float(a6 << 16) + __uint_as_float(a7 << 16);
        ay1 += __uint_as_float(a4 & 0xFFFF0000u) + __uint_as_float(a5 & 0xFFFF0000u)
             + __uint_as_float(a6 & 0xFFFF0000u) + __uint_as_float(a7 & 0xFFFF0000u);
        c4 = c4n; p = pn;
    }
    float ax = ax0 + ax1, ay = ay0 + ay1;
    uint ch = 2u * c2;
    size_t idx = (size_t)node * HID + ch;
    float2 hi = *(const float2*)(h_in + idx);
    float2 bb = *(const float2*)(b + ch);
    float d = dis[node];
    float2 o;
    o.x = hi.x + bb.x + d * ax;
    o.y = hi.y + bb.y + d * ay;
    *(float2*)(h_out + idx) = o;
}

__device__ __forceinline__ void convmm_body(int row, int c0, const float* __restrict__ h,
                                            const float* __restrict__ Ws,
                                            const float* __restrict__ dis,
                                            ushort* __restrict__ hWs) {
    float acc[16] = {0.f, 0.f, 0.f, 0.f, 0.f, 0.f, 0.f, 0.f,
                     0.f, 0.f, 0.f, 0.f, 0.f, 0.f, 0.f, 0.f};
    const float4* hr = (const float4*)(h + (size_t)row * HID);
    for (int k4 = 0; k4 < HID / 4; ++k4) {
        float4 hv = hr[k4];
        const float* wr = Ws + (k4 * 4) * HID + c0;
#pragma unroll
        for (int j = 0; j < 16; ++j) acc[j] = fmaf(hv.x, wr[j], acc[j]);
#pragma unroll
        for (int j = 0; j < 16; ++j) acc[j] = fmaf(hv.y, wr[HID + j], acc[j]);
#pragma unroll
        for (int j = 0; j < 16; ++j) acc[j] = fmaf(hv.z, wr[2 * HID + j], acc[j]);
#pragma unroll
        for (int j = 0; j < 16; ++j) acc[j] = fmaf(hv.w, wr[3 * HID + j], acc[j]);
    }
    float d = dis[row];
    ushort* o = hWs + (size_t)row * HID + c0;
#pragma unroll
    for (int j = 0; j < 16; ++j) {
        __hip_bfloat16 t = __float2bfloat16(d * acc[j]);
        o[j] = *(ushort*)&t;
    }
}

// ================= k_front: scatter | pack mh | pack hll | dummy init =================

__global__ void __launch_bounds__(256) k_front(const int* __restrict__ src,
                       const int* __restrict__ dst, int* __restrict__ gcur,
                       uint* __restrict__ ebuf,
                       const int* __restrict__ mh, uint* __restrict__ mhp,
                       uint* __restrict__ mhA,
                       const int* __restrict__ hll, uint* __restrict__ hp,
                       uint* __restrict__ hllA) {
    __shared__ uint ecache[EDGES_PER_BLK];
    __shared__ int cnt[NBUCK];
    __shared__ int cur[NBUCK];
    int b = blockIdx.x;
    int t = threadIdx.x;
    if (b < SCAT_BLOCKS) {
        for (int i = t; i < NBUCK; i += 256) cnt[i] = 0;
        __syncthreads();
        int e0 = b * EDGES_PER_BLK;
        for (int i = t; i < EDGES_PER_BLK; i += 256) {
            int d = dst[e0 + i];
            int s = src[e0 + i];
            ecache[i] = ((uint)s << 16) | (uint)d;   // both < 65536
            atomicAdd(&cnt[d >> BSHIFT], 1);
        }
        __syncthreads();
        for (int bb = t; bb < NBUCK; bb += 256)
            cur[bb] = bb * CAPB + atomicAdd(&gcur[bb], cnt[bb]);
        __syncthreads();
        for (int i = t; i < EDGES_PER_BLK; i += 256) {
            uint en = ecache[i];
            uint d = en & 0xFFFFu;
            int p = atomicAdd(&cur[d >> BSHIFT], 1);
            ebuf[p] = ((en >> 16) << BSHIFT) | (d & (BNODES - 1));
        }
    } else if (b < SCAT_BLOCKS + PACKMH_BLOCKS) {
        int i = (b - SCAT_BLOCKS) * 256 + t;
        int2 v = ((const int2*)mh)[i];
        uint u0 = __float_as_uint((float)v.x) >> 16;
        uint u1 = __float_as_uint((float)v.y) >> 16;
        mhp[i] = u0 | (u1 << 16);
    } else if (b < SCAT_BLOCKS + PACKMH_BLOCKS + HLL_BLOCKS) {
        int i = (b - SCAT_BLOCKS - PACKMH_BLOCKS) * 256 + t;
        int4 v = ((const int4*)hll)[i];
        hp[i] = (uint)v.x | ((uint)v.y << 8) | ((uint)v.z << 16) | ((uint)v.w << 24);
    } else {
        if (t < 64) {
            mhp[(size_t)DUMMY * 64 + t] = 0xFFFFFFFFu;
            mhA[(size_t)DUMMY * 64 + t] = 0xFFFFFFFFu;
        } else if (t < 80) {
            hp[(size_t)DUMMY * 16 + (t - 64)] = 0u;
        } else if (t < 96) {
            hllA[(size_t)DUMMY * 16 + (t - 80)] = 0u;
        }
    }
}

// ================= k_fat1: csr | encoder =================

__global__ void __launch_bounds__(256) k_fat1(const uint* __restrict__ ebuf,
                      const int* __restrict__ gcur, int* __restrict__ pcur,
                      int2* __restrict__ off2, float* __restrict__ dis,
                      ushort* __restrict__ csr,
                      const float* __restrict__ x, const float* __restrict__ W_enc,
                      const float* __restrict__ b_enc, float* __restrict__ h) {
    __shared__ uint smem[SLICE_CAP + BNODES + 256 + 1];   // ~35.8 KB
    int b = blockIdx.x;
    int t = threadIdx.x;
    if (b < NBUCK) {
        uint* slice = smem;
        int* lcur = (int*)(smem + SLICE_CAP);
        int* ssum = (int*)(smem + SLICE_CAP + BNODES);
        int* sbase = (int*)(smem + SLICE_CAP + BNODES + 256);
        int lo = b << BSHIFT;
        int nbkt = min(BNODES, N_NODES - lo);
        int ebase = b * CAPB;
        int ecnt = gcur[b];
        lcur[t] = 0;
        __syncthreads();
        for (int i = t; i < ecnt; i += 256)
            atomicAdd(&lcur[ebuf[ebase + i] & (BNODES - 1)], 1);
        __syncthreads();
        int a0 = lcur[t];                      // in-degree (excl self)
        int plen = (t < nbkt) ? ((a0 + 8) & ~7) : 0;   // padded length incl self
        ssum[t] = plen;
        __syncthreads();
        for (int off = 1; off < 256; off <<= 1) {
            int u = (t >= off) ? ssum[t - off] : 0;
            __syncthreads();
            ssum[t] += u;
            __syncthreads();
        }
        int ppre = ssum[t] - plen;
        if (t == 255) sbase[0] = atomicAdd(pcur, ssum[255]);
        __syncthreads();
        int base = sbase[0];
        if (t < nbkt) {
            slice[ppre] = (uint)(lo + t);      // self-loop first
            lcur[t] = ppre + 1;
            off2[lo + t] = make_int2(base + ppre, base + ppre + plen);
            dis[lo + t] = rsqrtf((float)(a0 + 1));
        }
        __syncthreads();
        for (int i = t; i < ecnt; i += 256) {
            uint en = ebuf[ebase + i];
            int p = atomicAdd(&lcur[en & (BNODES - 1)], 1);
            slice[p] = en >> BSHIFT;
        }
        __syncthreads();
        if (t < nbkt)
            for (int i = lcur[t]; i < ppre + plen; ++i) slice[i] = DUMMY;
        __syncthreads();
        int total = ssum[255];
        for (int i = t; i < total; i += 256) csr[base + i] = (ushort)slice[i];
    } else {
        float* Ws = (float*)smem;
        for (int idx = t; idx < FDIM * HID; idx += 256) Ws[idx] = W_enc[idx];
        __syncthreads();
        int row = (b - NBUCK) * 64 + (t >> 2);
        int c0 = (t & 3) * 16;
        if (row >= N_NODES) return;
        float acc[16];
#pragma unroll
        for (int j = 0; j < 16; ++j) acc[j] = b_enc[c0 + j];
        const float4* xr = (const float4*)(x + (size_t)row * FDIM);
        for (int k4 = 0; k4 < FDIM / 4; ++k4) {
            float4 xv = xr[k4];
            const float* wr = Ws + (k4 * 4) * HID + c0;
#pragma unroll
            for (int j = 0; j < 16; ++j) acc[j] = fmaf(xv.x, wr[j], acc[j]);
#pragma unroll
            for (int j = 0; j < 16; ++j) acc[j] = fmaf(xv.y, wr[HID + j], acc[j]);
#pragma unroll
            for (int j = 0; j < 16; ++j) acc[j] = fmaf(xv.z, wr[2 * HID + j], acc[j]);
#pragma unroll
            for (int j = 0; j < 16; ++j) acc[j] = fmaf(xv.w, wr[3 * HID + j], acc[j]);
        }
        float* hr = h + (size_t)row * HID + c0;
#pragma unroll
        for (int j = 0; j < 16; ++j) hr[j] = acc[j];
    }
}

// ================= D1: mh0 | hll0 | conv0 (no LDS: conv reads W via L1) =================

__global__ void __launch_bounds__(256) k_hopA(const int2* __restrict__ off2,
                    const ushort* __restrict__ csr,
                    const uint* __restrict__ mh_in, uint* __restrict__ mh_out_p,
                    const uint* __restrict__ hll_in, uint* __restrict__ hll_out_p,
                    float* __restrict__ cards,
                    const float* __restrict__ h, const float* __restrict__ W,
                    const float* __restrict__ dis, ushort* __restrict__ hWs) {
    int blk = blockIdx.x;
    int t = threadIdx.x;
    if (blk < MH2_BLOCKS) {
        int node = blk * 8 + (t >> 6) * 2 + ((t >> 5) & 1);
        mh_body(node, t & 31, off2, csr, mh_in, mh_out_p, nullptr);
    } else if (blk < MH2_BLOCKS + HLL_BLOCKS) {
        int node = (blk - MH2_BLOCKS) * 16 + (t >> 4);
        hll_body(node, t & 15, off2, csr, hll_in, hll_out_p, nullptr, cards, 0);
    } else {
        int row = (blk - MH2_BLOCKS - HLL_BLOCKS) * 64 + (t >> 2);
        int c0 = (t & 3) * 16;
        if (row > N_NODES) return;
        if (row == N_NODES) {           // dummy zero row
            ushort* o = hWs + (size_t)row * HID + c0;
#pragma unroll
            for (int j = 0; j < 16; ++j) o[j] = 0;
            return;
        }
        convmm_body(row, c0, h, W, dis, hWs);   // W from global (L1-hot, 16 KB shared)
    }
}

// ================= D2: mh1 | agg0 | hll1 =================

__global__ void __launch_bounds__(256) k_hopB(const int2* __restrict__ off2,
                    const ushort* __restrict__ csr,
                    const uint* __restrict__ mh_in, float* __restrict__ mh_out_f,
                    const uint* __restrict__ hWs32, const float* __restrict__ b0,
                    float* __restrict__ h_cur,
                    const uint* __restrict__ hll_in, float* __restrict__ hll_out_f,
                    float* __restrict__ cards, const float* __restrict__ dis) {
    int blk = blockIdx.x;
    int t = threadIdx.x;
    if (blk < MH2_BLOCKS) {
        int node = blk * 8 + (t >> 6) * 2 + ((t >> 5) & 1);
        mh_body(node, t & 31, off2, csr, mh_in, nullptr, mh_out_f);
    } else if (blk < MH2_BLOCKS + AGG2_BLOCKS) {
        int node = (blk - MH2_BLOCKS) * 8 + (t >> 6) * 2 + ((t >> 5) & 1);
        agg_body(node, t & 31, off2, csr, hWs32, dis, b0, h_cur, h_cur);
    } else {
        int node = (blk - MH2_BLOCKS - AGG2_BLOCKS) * 16 + (t >> 4);
        hll_body(node, t & 15, off2, csr, hll_in, nullptr, hll_out_f, cards, 1);
    }
}

// ================= D3: conv1 =================

__global__ void __launch_bounds__(256) k_conv(const float* __restrict__ h,
                         const float* __restrict__ W, const float* __restrict__ dis,
                         ushort* __restrict__ hWs) {
    __shared__ float Ws[HID * HID];
    for (int i = threadIdx.x; i < HID * HID; i += 256) Ws[i] = W[i];
    __syncthreads();
    int row = blockIdx.x * 64 + (threadIdx.x >> 2);
    int c0 = (threadIdx.x & 3) * 16;
    if (row > N_NODES) return;
    if (row == N_NODES) {
        ushort* o = hWs + (size_t)row * HID + c0;
#pragma unroll
        for (int j = 0; j < 16; ++j) o[j] = 0;
        return;
    }
    convmm_body(row, c0, h, Ws, dis, hWs);
}

// ================= D4: agg1 -> out_h =================

__global__ void __launch_bounds__(256) k_agg(const int2* __restrict__ off2,
                      const ushort* __restrict__ csr, const uint* __restrict__ hWs32,
                      const float* __restrict__ dis, const float* __restrict__ b,
                      const float* __restrict__ h_in, float* __restrict__ h_out) {
    int t = threadIdx.x;
    int node = blockIdx.x * 8 + (t >> 6) * 2 + ((t >> 5) & 1);
    agg_body(node, t & 31, off2, csr, hWs32, dis, b, h_in, h_out);
}

// ---------------- driver ----------------

static inline char* align256(char* p) {
    return (char*)(((uintptr_t)p + 255) & ~(uintptr_t)255);
}

extern "C" void kernel_launch(void* const* d_in, const int* in_sizes, int n_in,
                              void* d_out, int out_size, void* d_ws, size_t ws_size,
                              hipStream_t stream) {
    const float* x       = (const float*)d_in[0];
    const int*   ei      = (const int*)d_in[1];
    const int*   mh0     = (const int*)d_in[2];
    const int*   hll0    = (const int*)d_in[3];
    const float* W_enc   = (const float*)d_in[4];
    const float* b_enc   = (const float*)d_in[5];
    const float* W_convs = (const float*)d_in[6];
    const float* b_convs = (const float*)d_in[7];

    float* out       = (float*)d_out;
    float* out_h     = out;
    float* out_cards = out + (size_t)N_NODES * HID;
    float* out_mh    = out_cards + (size_t)N_NODES * 2;
    float* out_hll   = out_mh + (size_t)N_NODES * NPERM;

    char* w = (char*)d_ws;
    int*   gcur    = (int*)w;   w += (size_t)NBUCK * 4;
    int*   pcur    = (int*)w;   w = align256(w + 4);
    int2*  off2    = (int2*)w;  w = align256(w + (size_t)N_NODES * 8);
    float* dis     = (float*)w; w = align256(w + (size_t)N_NODES * 4);
    ushort* csr    = (ushort*)w; w = align256(w + (size_t)(N_EDGES + 8 * N_NODES) * 2);
    uint*  mhp0    = (uint*)w;  w = align256(w + (size_t)(N_NODES + 1) * 64 * 4);
    uint*  mhA     = (uint*)w;  w = align256(w + (size_t)(N_NODES + 1) * 64 * 4);
    uint*  hp0     = (uint*)w;  w = align256(w + (size_t)(N_NODES + 1) * 16 * 4);
    uint*  hllA    = (uint*)w;  w = align256(w + (size_t)(N_NODES + 1) * 16 * 4);
    float* h_cur   = (float*)w; w = align256(w + (size_t)N_NODES * HID * 4);
    ushort* hWs    = (ushort*)w; w = align256(w + (size_t)(N_NODES + 1) * HID * 2);
    uint*  ebuf    = mhA;  // build-phase alias (196*6144 uints = 4.8MB < 12.8MB extent);
                           // dummy row at 12.8MB offset untouched by ebuf

    const int* src = ei;
    const int* dst = ei + N_EDGES;

    // zero gcur (+pcur, adjacent) -> fixed bucket bases added in-kernel
    hipMemsetAsync(gcur, 0, (size_t)(NBUCK + 1) * 4, stream);
    // F1: scatter | pack mh | pack hll | dummy init
    k_front<<<SCAT_BLOCKS + PACKMH_BLOCKS + HLL_BLOCKS + 1, 256, 0, stream>>>(
        src, dst, gcur, ebuf, mh0, mhp0, mhA, hll0, hp0, hllA);
    // F2: csr | encoder
    k_fat1<<<NBUCK + CONV_BLOCKS, 256, 0, stream>>>(
        ebuf, gcur, pcur, off2, dis, csr, x, W_enc, b_enc, h_cur);

    // D1: mh0 | hll0 | conv0
    k_hopA<<<MH2_BLOCKS + HLL_BLOCKS + CONV_BLOCKS + 1, 256, 0, stream>>>(
        off2, csr, mhp0, mhA, hp0, hllA, out_cards, h_cur, W_convs, dis, hWs);
    // D2: mh1 | agg0 | hll1
    k_hopB<<<MH2_BLOCKS + AGG2_BLOCKS + HLL_BLOCKS, 256, 0, stream>>>(
        off2, csr, mhA, out_mh, (const uint*)hWs, b_convs, h_cur, hllA, out_hll, out_cards, dis);
    // D3: conv1
    k_conv<<<CONV_BLOCKS + 1, 256, 0, stream>>>(h_cur, W_convs + HID * HID, dis, hWs);
    // D4: agg1 -> out_h
    k_agg<<<AGG2_BLOCKS, 256, 0, stream>>>(off2, csr, (const uint*)hWs, dis, b_convs + HID, h_cur, out_h);
}

// Round 16
// 176.817 us; speedup vs baseline: 1.3172x; 1.3172x over previous
//
#include <hip/hip_runtime.h>
#include <hip/hip_bf16.h>

typedef unsigned int uint;
typedef unsigned short ushort;

#define N_NODES 50000
#define N_EDGES 800000
#define FDIM 128
#define HID 64
#define NPERM 128
#define HLLM 64
#define DUMMY 50000                // identity row index

#define BSHIFT 8
#define BNODES 256                 // nodes per bucket
#define NBUCK 196                  // ceil(50000/256)
#define CAPB 6144                  // fixed ebuf capacity/bucket (mean 4096, 32 sigma)
#define SCAT_BLOCKS 256
#define EDGES_PER_BLK 3125         // 800000/256 exactly
#define PACKMH_BLOCKS 12500
#define MH2_BLOCKS 6250            // 8 nodes/block (2 per wave)
#define AGG2_BLOCKS 6250
#define HLL_BLOCKS 3125            // 16 nodes/block
#define SLICE_CAP 8448
#define CONV_BLOCKS 782            // ceil(50000/64)

__device__ __forceinline__ uint pk_min_u16(uint a, uint b) {
    uint d;
    asm("v_pk_min_u16 %0, %1, %2" : "=v"(d) : "v"(a), "v"(b));
    return d;
}

// ========== mh: 2 nodes/wave (lanes 0-31 / 32-63), uint2/lane, csr prefetch ==========

__device__ __forceinline__ void mh_body(int node, uint c2, const int2* __restrict__ off2,
                                        const ushort* __restrict__ csr,
                                        const uint* __restrict__ mh_in,
                                        uint* __restrict__ out_p, float* __restrict__ out_f) {
    int2 se = off2[node];
    uint mnA = 0xFFFFFFFFu, mnB = 0xFFFFFFFFu, mnC = 0xFFFFFFFFu, mnD = 0xFFFFFFFFu;
    int p = se.x;
    uint4 c4 = *(const uint4*)(csr + p);
    for (; p < se.y; ) {
        int pn = p + 8;
        uint4 c4n = *(const uint4*)(csr + pn);   // 16B over-read at end is in-allocation slack
        uint j0 = c4.x & 0xFFFFu, j1 = c4.x >> 16;
        uint j2 = c4.y & 0xFFFFu, j3 = c4.y >> 16;
        uint j4 = c4.z & 0xFFFFu, j5 = c4.z >> 16;
        uint j6 = c4.w & 0xFFFFu, j7 = c4.w >> 16;
        uint2 a0 = *(const uint2*)(mh_in + j0 * 64u + 2u * c2);
        uint2 a1 = *(const uint2*)(mh_in + j1 * 64u + 2u * c2);
        uint2 a2 = *(const uint2*)(mh_in + j2 * 64u + 2u * c2);
        uint2 a3 = *(const uint2*)(mh_in + j3 * 64u + 2u * c2);
        uint2 a4 = *(const uint2*)(mh_in + j4 * 64u + 2u * c2);
        uint2 a5 = *(const uint2*)(mh_in + j5 * 64u + 2u * c2);
        uint2 a6 = *(const uint2*)(mh_in + j6 * 64u + 2u * c2);
        uint2 a7 = *(const uint2*)(mh_in + j7 * 64u + 2u * c2);
        mnA = pk_min_u16(mnA, a0.x); mnB = pk_min_u16(mnB, a0.y);
        mnC = pk_min_u16(mnC, a1.x); mnD = pk_min_u16(mnD, a1.y);
        mnA = pk_min_u16(mnA, a2.x); mnB = pk_min_u16(mnB, a2.y);
        mnC = pk_min_u16(mnC, a3.x); mnD = pk_min_u16(mnD, a3.y);
        mnA = pk_min_u16(mnA, a4.x); mnB = pk_min_u16(mnB, a4.y);
        mnC = pk_min_u16(mnC, a5.x); mnD = pk_min_u16(mnD, a5.y);
        mnA = pk_min_u16(mnA, a6.x); mnB = pk_min_u16(mnB, a6.y);
        mnC = pk_min_u16(mnC, a7.x); mnD = pk_min_u16(mnD, a7.y);
        c4 = c4n; p = pn;
    }
    uint m0 = pk_min_u16(mnA, mnC);
    uint m1 = pk_min_u16(mnB, mnD);
    if (out_p) {
        uint2 w = {m0, m1};
        *(uint2*)(out_p + (size_t)node * 64 + 2u * c2) = w;
    } else {
        float4 w;
        w.x = __uint_as_float((m0 & 0xFFFFu) << 16);
        w.y = __uint_as_float(m0 & 0xFFFF0000u);
        w.z = __uint_as_float((m1 & 0xFFFFu) << 16);
        w.w = __uint_as_float(m1 & 0xFFFF0000u);
        *(float4*)(out_f + (size_t)node * NPERM + 4u * c2) = w;
    }
}

// ========== hll: 16 lanes/node, uint/lane, csr prefetch ==========

__device__ __forceinline__ void hll_body(int node, uint q, const int2* __restrict__ off2,
                                         const ushort* __restrict__ csr,
                                         const uint* __restrict__ hll_in,
                                         uint* __restrict__ out_p, float* __restrict__ out_f,
                                         float* __restrict__ cards, int kcol) {
    int2 se = off2[node];
    uint m0 = 0, m1 = 0, m2 = 0, m3 = 0;
#define HLL_ACC(vv) do { uint _v = (vv); \
        m0 = max(m0, _v & 0xFFu); m1 = max(m1, (_v >> 8) & 0xFFu); \
        m2 = max(m2, (_v >> 16) & 0xFFu); m3 = max(m3, _v >> 24); } while (0)
    int p = se.x;
    uint4 c4 = *(const uint4*)(csr + p);
    for (; p < se.y; ) {
        int pn = p + 8;
        uint4 c4n = *(const uint4*)(csr + pn);
        uint j0 = c4.x & 0xFFFFu, j1 = c4.x >> 16;
        uint j2 = c4.y & 0xFFFFu, j3 = c4.y >> 16;
        uint j4 = c4.z & 0xFFFFu, j5 = c4.z >> 16;
        uint j6 = c4.w & 0xFFFFu, j7 = c4.w >> 16;
        uint a0 = hll_in[j0 * 16u + q];
        uint a1 = hll_in[j1 * 16u + q];
        uint a2 = hll_in[j2 * 16u + q];
        uint a3 = hll_in[j3 * 16u + q];
        uint a4 = hll_in[j4 * 16u + q];
        uint a5 = hll_in[j5 * 16u + q];
        uint a6 = hll_in[j6 * 16u + q];
        uint a7 = hll_in[j7 * 16u + q];
        HLL_ACC(a0); HLL_ACC(a1); HLL_ACC(a2); HLL_ACC(a3);
        HLL_ACC(a4); HLL_ACC(a5); HLL_ACC(a6); HLL_ACC(a7);
        c4 = c4n; p = pn;
    }
#undef HLL_ACC
    if (out_p) out_p[(size_t)node * 16 + q] = m0 | (m1 << 8) | (m2 << 16) | (m3 << 24);
    if (out_f) {
        float4 w = {(float)m0, (float)m1, (float)m2, (float)m3};
        *(float4*)(out_f + (size_t)node * HLLM + 4 * q) = w;
    }
    float v = exp2f(-(float)m0) + exp2f(-(float)m1) + exp2f(-(float)m2) + exp2f(-(float)m3);
    v += __shfl_xor(v, 1); v += __shfl_xor(v, 2);
    v += __shfl_xor(v, 4); v += __shfl_xor(v, 8);
    if (q == 0) {
        const float alphamm = (float)(0.7213 / (1.0 + 1.079 / 64.0) * 64.0 * 64.0);
        cards[(size_t)node * 2 + kcol] = alphamm / v;
    }
}

// ========== agg: 2 nodes/wave, uint/lane (2 channels), csr prefetch ==========

__device__ __forceinline__ void agg_body(int node, uint c2, const int2* __restrict__ off2,
                                         const ushort* __restrict__ csr,
                                         const uint* __restrict__ hWs32,
                                         const float* __restrict__ dis,
                                         const float* __restrict__ b,
                                         const float* __restrict__ h_in,
                                         float* __restrict__ h_out) {
    int2 se = off2[node];
    float ax0 = 0.f, ay0 = 0.f, ax1 = 0.f, ay1 = 0.f;
    int p = se.x;
    uint4 c4 = *(const uint4*)(csr + p);
    for (; p < se.y; ) {
        int pn = p + 8;
        uint4 c4n = *(const uint4*)(csr + pn);
        uint j0 = c4.x & 0xFFFFu, j1 = c4.x >> 16;
        uint j2 = c4.y & 0xFFFFu, j3 = c4.y >> 16;
        uint j4 = c4.z & 0xFFFFu, j5 = c4.z >> 16;
        uint j6 = c4.w & 0xFFFFu, j7 = c4.w >> 16;
        uint a0 = hWs32[j0 * 32u + c2];
        uint a1 = hWs32[j1 * 32u + c2];
        uint a2 = hWs32[j2 * 32u + c2];
        uint a3 = hWs32[j3 * 32u + c2];
        uint a4 = hWs32[j4 * 32u + c2];
        uint a5 = hWs32[j5 * 32u + c2];
        uint a6 = hWs32[j6 * 32u + c2];
        uint a7 = hWs32[j7 * 32u + c2];
        ax0 += __uint_as_float(a0 << 16) + __uint_as_float(a1 << 16)
             + __uint_as_float(a2 << 16) + __uint_as_float(a3 << 16);
        ay0 += __uint_as_float(a0 & 0xFFFF0000u) + __uint_as_float(a1 & 0xFFFF0000u)
             + __uint_as_float(a2 & 0xFFFF0000u) + __uint_as_float(a3 & 0xFFFF0000u);
        ax1 += __uint_as_float(a4 << 16) + __uint_as_float(a5 << 16)
             + __uint_as_float(a6 << 16) + __uint_as_float(a7 << 16);
        ay1 += __uint_as_float(a4 & 0xFFFF0000u) + __uint_as_float(a5 & 0xFFFF0000u)
             + __uint_as_float(a6 & 0xFFFF0000u) + __uint_as_float(a7 & 0xFFFF0000u);
        c4 = c4n; p = pn;
    }
    float ax = ax0 + ax1, ay = ay0 + ay1;
    uint ch = 2u * c2;
    size_t idx = (size_t)node * HID + ch;
    float2 hi = *(const float2*)(h_in + idx);
    float2 bb = *(const float2*)(b + ch);
    float d = dis[node];
    float2 o;
    o.x = hi.x + bb.x + d * ax;
    o.y = hi.y + bb.y + d * ay;
    *(float2*)(h_out + idx) = o;
}

__device__ __forceinline__ void convmm_body(int row, int c0, const float* __restrict__ h,
                                            const float* __restrict__ Ws,
                                            const float* __restrict__ dis,
                                            ushort* __restrict__ hWs) {
    float acc[16] = {0.f, 0.f, 0.f, 0.f, 0.f, 0.f, 0.f, 0.f,
                     0.f, 0.f, 0.f, 0.f, 0.f, 0.f, 0.f, 0.f};
    const float4* hr = (const float4*)(h + (size_t)row * HID);
    for (int k4 = 0; k4 < HID / 4; ++k4) {
        float4 hv = hr[k4];
        const float* wr = Ws + (k4 * 4) * HID + c0;
#pragma unroll
        for (int j = 0; j < 16; ++j) acc[j] = fmaf(hv.x, wr[j], acc[j]);
#pragma unroll
        for (int j = 0; j < 16; ++j) acc[j] = fmaf(hv.y, wr[HID + j], acc[j]);
#pragma unroll
        for (int j = 0; j < 16; ++j) acc[j] = fmaf(hv.z, wr[2 * HID + j], acc[j]);
#pragma unroll
        for (int j = 0; j < 16; ++j) acc[j] = fmaf(hv.w, wr[3 * HID + j], acc[j]);
    }
    float d = dis[row];
    ushort* o = hWs + (size_t)row * HID + c0;
#pragma unroll
    for (int j = 0; j < 16; ++j) {
        __hip_bfloat16 t = __float2bfloat16(d * acc[j]);
        o[j] = *(ushort*)&t;
    }
}

// ================= k_front: scatter | pack mh | pack hll | dummy init =================

__global__ void __launch_bounds__(256) k_front(const int* __restrict__ src,
                       const int* __restrict__ dst, int* __restrict__ gcur,
                       uint* __restrict__ ebuf,
                       const int* __restrict__ mh, uint* __restrict__ mhp,
                       uint* __restrict__ mhA,
                       const int* __restrict__ hll, uint* __restrict__ hp,
                       uint* __restrict__ hllA) {
    __shared__ uint ecache[EDGES_PER_BLK];
    __shared__ int cnt[NBUCK];
    __shared__ int cur[NBUCK];
    int b = blockIdx.x;
    int t = threadIdx.x;
    if (b < SCAT_BLOCKS) {
        for (int i = t; i < NBUCK; i += 256) cnt[i] = 0;
        __syncthreads();
        int e0 = b * EDGES_PER_BLK;
        for (int i = t; i < EDGES_PER_BLK; i += 256) {
            int d = dst[e0 + i];
            int s = src[e0 + i];
            ecache[i] = ((uint)s << 16) | (uint)d;   // both < 65536
            atomicAdd(&cnt[d >> BSHIFT], 1);
        }
        __syncthreads();
        for (int bb = t; bb < NBUCK; bb += 256)
            cur[bb] = bb * CAPB + atomicAdd(&gcur[bb], cnt[bb]);
        __syncthreads();
        for (int i = t; i < EDGES_PER_BLK; i += 256) {
            uint en = ecache[i];
            uint d = en & 0xFFFFu;
            int p = atomicAdd(&cur[d >> BSHIFT], 1);
            ebuf[p] = ((en >> 16) << BSHIFT) | (d & (BNODES - 1));
        }
    } else if (b < SCAT_BLOCKS + PACKMH_BLOCKS) {
        int i = (b - SCAT_BLOCKS) * 256 + t;
        int2 v = ((const int2*)mh)[i];
        uint u0 = __float_as_uint((float)v.x) >> 16;
        uint u1 = __float_as_uint((float)v.y) >> 16;
        mhp[i] = u0 | (u1 << 16);
    } else if (b < SCAT_BLOCKS + PACKMH_BLOCKS + HLL_BLOCKS) {
        int i = (b - SCAT_BLOCKS - PACKMH_BLOCKS) * 256 + t;
        int4 v = ((const int4*)hll)[i];
        hp[i] = (uint)v.x | ((uint)v.y << 8) | ((uint)v.z << 16) | ((uint)v.w << 24);
    } else {
        if (t < 64) {
            mhp[(size_t)DUMMY * 64 + t] = 0xFFFFFFFFu;
            mhA[(size_t)DUMMY * 64 + t] = 0xFFFFFFFFu;
        } else if (t < 80) {
            hp[(size_t)DUMMY * 16 + (t - 64)] = 0u;
        } else if (t < 96) {
            hllA[(size_t)DUMMY * 16 + (t - 80)] = 0u;
        }
    }
}

// ================= k_fat1: csr | encoder =================

__global__ void __launch_bounds__(256) k_fat1(const uint* __restrict__ ebuf,
                      const int* __restrict__ gcur, int* __restrict__ pcur,
                      int2* __restrict__ off2, float* __restrict__ dis,
                      ushort* __restrict__ csr,
                      const float* __restrict__ x, const float* __restrict__ W_enc,
                      const float* __restrict__ b_enc, float* __restrict__ h) {
    __shared__ uint smem[SLICE_CAP + BNODES + 256 + 1];   // ~35.8 KB
    int b = blockIdx.x;
    int t = threadIdx.x;
    if (b < NBUCK) {
        uint* slice = smem;
        int* lcur = (int*)(smem + SLICE_CAP);
        int* ssum = (int*)(smem + SLICE_CAP + BNODES);
        int* sbase = (int*)(smem + SLICE_CAP + BNODES + 256);
        int lo = b << BSHIFT;
        int nbkt = min(BNODES, N_NODES - lo);
        int ebase = b * CAPB;
        int ecnt = gcur[b];
        lcur[t] = 0;
        __syncthreads();
        for (int i = t; i < ecnt; i += 256)
            atomicAdd(&lcur[ebuf[ebase + i] & (BNODES - 1)], 1);
        __syncthreads();
        int a0 = lcur[t];                      // in-degree (excl self)
        int plen = (t < nbkt) ? ((a0 + 8) & ~7) : 0;   // padded length incl self
        ssum[t] = plen;
        __syncthreads();
        for (int off = 1; off < 256; off <<= 1) {
            int u = (t >= off) ? ssum[t - off] : 0;
            __syncthreads();
            ssum[t] += u;
            __syncthreads();
        }
        int ppre = ssum[t] - plen;
        if (t == 255) sbase[0] = atomicAdd(pcur, ssum[255]);
        __syncthreads();
        int base = sbase[0];
        if (t < nbkt) {
            slice[ppre] = (uint)(lo + t);      // self-loop first
            lcur[t] = ppre + 1;
            off2[lo + t] = make_int2(base + ppre, base + ppre + plen);
            dis[lo + t] = rsqrtf((float)(a0 + 1));
        }
        __syncthreads();
        for (int i = t; i < ecnt; i += 256) {
            uint en = ebuf[ebase + i];
            int p = atomicAdd(&lcur[en & (BNODES - 1)], 1);
            slice[p] = en >> BSHIFT;
        }
        __syncthreads();
        if (t < nbkt)
            for (int i = lcur[t]; i < ppre + plen; ++i) slice[i] = DUMMY;
        __syncthreads();
        int total = ssum[255];
        for (int i = t; i < total; i += 256) csr[base + i] = (ushort)slice[i];
    } else {
        float* Ws = (float*)smem;
        for (int idx = t; idx < FDIM * HID; idx += 256) Ws[idx] = W_enc[idx];
        __syncthreads();
        int row = (b - NBUCK) * 64 + (t >> 2);
        int c0 = (t & 3) * 16;
        if (row >= N_NODES) return;
        float acc[16];
#pragma unroll
        for (int j = 0; j < 16; ++j) acc[j] = b_enc[c0 + j];
        const float4* xr = (const float4*)(x + (size_t)row * FDIM);
        for (int k4 = 0; k4 < FDIM / 4; ++k4) {
            float4 xv = xr[k4];
            const float* wr = Ws + (k4 * 4) * HID + c0;
#pragma unroll
            for (int j = 0; j < 16; ++j) acc[j] = fmaf(xv.x, wr[j], acc[j]);
#pragma unroll
            for (int j = 0; j < 16; ++j) acc[j] = fmaf(xv.y, wr[HID + j], acc[j]);
#pragma unroll
            for (int j = 0; j < 16; ++j) acc[j] = fmaf(xv.z, wr[2 * HID + j], acc[j]);
#pragma unroll
            for (int j = 0; j < 16; ++j) acc[j] = fmaf(xv.w, wr[3 * HID + j], acc[j]);
        }
        float* hr = h + (size_t)row * HID + c0;
#pragma unroll
        for (int j = 0; j < 16; ++j) hr[j] = acc[j];
    }
}

// ================= D1: mh0 | hll0 | conv0 (conv uses LDS W tile) =================

__global__ void __launch_bounds__(256) k_hopA(const int2* __restrict__ off2,
                    const ushort* __restrict__ csr,
                    const uint* __restrict__ mh_in, uint* __restrict__ mh_out_p,
                    const uint* __restrict__ hll_in, uint* __restrict__ hll_out_p,
                    float* __restrict__ cards,
                    const float* __restrict__ h, const float* __restrict__ W,
                    const float* __restrict__ dis, ushort* __restrict__ hWs) {
    __shared__ float Ws[HID * HID];   // 16 KB; 10 blocks/CU possible, not limiting
    int blk = blockIdx.x;
    int t = threadIdx.x;
    if (blk < MH2_BLOCKS) {
        int node = blk * 8 + (t >> 6) * 2 + ((t >> 5) & 1);
        mh_body(node, t & 31, off2, csr, mh_in, mh_out_p, nullptr);
    } else if (blk < MH2_BLOCKS + HLL_BLOCKS) {
        int node = (blk - MH2_BLOCKS) * 16 + (t >> 4);
        hll_body(node, t & 15, off2, csr, hll_in, hll_out_p, nullptr, cards, 0);
    } else {
        for (int i = t; i < HID * HID; i += 256) Ws[i] = W[i];
        __syncthreads();
        int row = (blk - MH2_BLOCKS - HLL_BLOCKS) * 64 + (t >> 2);
        int c0 = (t & 3) * 16;
        if (row > N_NODES) return;
        if (row == N_NODES) {           // dummy zero row
            ushort* o = hWs + (size_t)row * HID + c0;
#pragma unroll
            for (int j = 0; j < 16; ++j) o[j] = 0;
            return;
        }
        convmm_body(row, c0, h, Ws, dis, hWs);
    }
}

// ================= D2: mh1 | agg0 | hll1 =================

__global__ void __launch_bounds__(256) k_hopB(const int2* __restrict__ off2,
                    const ushort* __restrict__ csr,
                    const uint* __restrict__ mh_in, float* __restrict__ mh_out_f,
                    const uint* __restrict__ hWs32, const float* __restrict__ b0,
                    float* __restrict__ h_cur,
                    const uint* __restrict__ hll_in, float* __restrict__ hll_out_f,
                    float* __restrict__ cards, const float* __restrict__ dis) {
    int blk = blockIdx.x;
    int t = threadIdx.x;
    if (blk < MH2_BLOCKS) {
        int node = blk * 8 + (t >> 6) * 2 + ((t >> 5) & 1);
        mh_body(node, t & 31, off2, csr, mh_in, nullptr, mh_out_f);
    } else if (blk < MH2_BLOCKS + AGG2_BLOCKS) {
        int node = (blk - MH2_BLOCKS) * 8 + (t >> 6) * 2 + ((t >> 5) & 1);
        agg_body(node, t & 31, off2, csr, hWs32, dis, b0, h_cur, h_cur);
    } else {
        int node = (blk - MH2_BLOCKS - AGG2_BLOCKS) * 16 + (t >> 4);
        hll_body(node, t & 15, off2, csr, hll_in, nullptr, hll_out_f, cards, 1);
    }
}

// ================= D3: conv1 =================

__global__ void __launch_bounds__(256) k_conv(const float* __restrict__ h,
                         const float* __restrict__ W, const float* __restrict__ dis,
                         ushort* __restrict__ hWs) {
    __shared__ float Ws[HID * HID];
    for (int i = threadIdx.x; i < HID * HID; i += 256) Ws[i] = W[i];
    __syncthreads();
    int row = blockIdx.x * 64 + (threadIdx.x >> 2);
    int c0 = (threadIdx.x & 3) * 16;
    if (row > N_NODES) return;
    if (row == N_NODES) {
        ushort* o = hWs + (size_t)row * HID + c0;
#pragma unroll
        for (int j = 0; j < 16; ++j) o[j] = 0;
        return;
    }
    convmm_body(row, c0, h, Ws, dis, hWs);
}

// ================= D4: agg1 -> out_h =================

__global__ void __launch_bounds__(256) k_agg(const int2* __restrict__ off2,
                      const ushort* __restrict__ csr, const uint* __restrict__ hWs32,
                      const float* __restrict__ dis, const float* __restrict__ b,
                      const float* __restrict__ h_in, float* __restrict__ h_out) {
    int t = threadIdx.x;
    int node = blockIdx.x * 8 + (t >> 6) * 2 + ((t >> 5) & 1);
    agg_body(node, t & 31, off2, csr, hWs32, dis, b, h_in, h_out);
}

// ---------------- driver ----------------

static inline char* align256(char* p) {
    return (char*)(((uintptr_t)p + 255) & ~(uintptr_t)255);
}

extern "C" void kernel_launch(void* const* d_in, const int* in_sizes, int n_in,
                              void* d_out, int out_size, void* d_ws, size_t ws_size,
                              hipStream_t stream) {
    const float* x       = (const float*)d_in[0];
    const int*   ei      = (const int*)d_in[1];
    const int*   mh0     = (const int*)d_in[2];
    const int*   hll0    = (const int*)d_in[3];
    const float* W_enc   = (const float*)d_in[4];
    const float* b_enc   = (const float*)d_in[5];
    const float* W_convs = (const float*)d_in[6];
    const float* b_convs = (const float*)d_in[7];

    float* out       = (float*)d_out;
    float* out_h     = out;
    float* out_cards = out + (size_t)N_NODES * HID;
    float* out_mh    = out_cards + (size_t)N_NODES * 2;
    float* out_hll   = out_mh + (size_t)N_NODES * NPERM;

    char* w = (char*)d_ws;
    int*   gcur    = (int*)w;   w += (size_t)NBUCK * 4;
    int*   pcur    = (int*)w;   w = align256(w + 4);
    int2*  off2    = (int2*)w;  w = align256(w + (size_t)N_NODES * 8);
    float* dis     = (float*)w; w = align256(w + (size_t)N_NODES * 4);
    ushort* csr    = (ushort*)w; w = align256(w + (size_t)(N_EDGES + 8 * N_NODES + 16) * 2);
    uint*  mhp0    = (uint*)w;  w = align256(w + (size_t)(N_NODES + 1) * 64 * 4);
    uint*  mhA     = (uint*)w;  w = align256(w + (size_t)(N_NODES + 1) * 64 * 4);
    uint*  hp0     = (uint*)w;  w = align256(w + (size_t)(N_NODES + 1) * 16 * 4);
    uint*  hllA    = (uint*)w;  w = align256(w + (size_t)(N_NODES + 1) * 16 * 4);
    float* h_cur   = (float*)w; w = align256(w + (size_t)N_NODES * HID * 4);
    ushort* hWs    = (ushort*)w; w = align256(w + (size_t)(N_NODES + 1) * HID * 2);
    uint*  ebuf    = mhA;  // build-phase alias (196*6144 uints = 4.8MB < 12.8MB extent);
                           // dummy row at 12.8MB offset untouched by ebuf

    const int* src = ei;
    const int* dst = ei + N_EDGES;

    // zero gcur (+pcur, adjacent) -> fixed bucket bases added in-kernel
    hipMemsetAsync(gcur, 0, (size_t)(NBUCK + 1) * 4, stream);
    // F1: scatter | pack mh | pack hll | dummy init
    k_front<<<SCAT_BLOCKS + PACKMH_BLOCKS + HLL_BLOCKS + 1, 256, 0, stream>>>(
        src, dst, gcur, ebuf, mh0, mhp0, mhA, hll0, hp0, hllA);
    // F2: csr | encoder
    k_fat1<<<NBUCK + CONV_BLOCKS, 256, 0, stream>>>(
        ebuf, gcur, pcur, off2, dis, csr, x, W_enc, b_enc, h_cur);

    // D1: mh0 | hll0 | conv0
    k_hopA<<<MH2_BLOCKS + HLL_BLOCKS + CONV_BLOCKS + 1, 256, 0, stream>>>(
        off2, csr, mhp0, mhA, hp0, hllA, out_cards, h_cur, W_convs, dis, hWs);
    // D2: mh1 | agg0 | hll1
    k_hopB<<<MH2_BLOCKS + AGG2_BLOCKS + HLL_BLOCKS, 256, 0, stream>>>(
        off2, csr, mhA, out_mh, (const uint*)hWs, b_convs, h_cur, hllA, out_hll, out_cards, dis);
    // D3: conv1
    k_conv<<<CONV_BLOCKS + 1, 256, 0, stream>>>(h_cur, W_convs + HID * HID, dis, hWs);
    // D4: agg1 -> out_h
    k_agg<<<AGG2_BLOCKS, 256, 0, stream>>>(off2, csr, (const uint*)hWs, dis, b_convs + HID, h_cur, out_h);
}

// Round 17
// 176.117 us; speedup vs baseline: 1.3225x; 1.0040x over previous
//
#include <hip/hip_runtime.h>
#include <hip/hip_bf16.h>

typedef unsigned int uint;
typedef unsigned short ushort;

#define N_NODES 50000
#define N_EDGES 800000
#define FDIM 128
#define HID 64
#define NPERM 128
#define HLLM 64
#define DUMMY 50000                // identity row index

#define BSHIFT 8
#define BNODES 256                 // nodes per bucket
#define NBUCK 196                  // ceil(50000/256)
#define CAPB 6144                  // fixed ebuf capacity/bucket (mean 4096, 32 sigma)
#define SCAT_BLOCKS 256
#define EDGES_PER_BLK 3125         // 800000/256 exactly
#define PACKMH_BLOCKS 12500
#define MH2_BLOCKS 6250            // 8 nodes/block (2 per wave)
#define AGG2_BLOCKS 6250
#define HLL_BLOCKS 3125            // 16 nodes/block
#define SLICE_CAP 8448
#define CONV_BLOCKS 782            // ceil(50000/64)

__device__ __forceinline__ uint pk_min_u16(uint a, uint b) {
    uint d;
    asm("v_pk_min_u16 %0, %1, %2" : "=v"(d) : "v"(a), "v"(b));
    return d;
}

// ========== mh: 2 nodes/wave, uint2/lane, SOFTWARE-PIPELINED row loads ==========
// Group g's rows reduce only after group g+1's loads are issued -> 16 rows in flight.

__device__ __forceinline__ void mh_body(int node, uint c2, const int2* __restrict__ off2,
                                        const ushort* __restrict__ csr,
                                        const uint* __restrict__ mh_in,
                                        uint* __restrict__ out_p, float* __restrict__ out_f) {
    int2 se = off2[node];
    uint mnA = 0xFFFFFFFFu, mnB = 0xFFFFFFFFu, mnC = 0xFFFFFFFFu, mnD = 0xFFFFFFFFu;
    uint co = 2u * c2;
    int p = se.x;
    uint4 c4 = *(const uint4*)(csr + p);
    uint4 c4n = *(const uint4*)(csr + p + 8);      // over-read lands in pad/slack
    uint2 r0 = *(const uint2*)(mh_in + (c4.x & 0xFFFFu) * 64u + co);
    uint2 r1 = *(const uint2*)(mh_in + (c4.x >> 16) * 64u + co);
    uint2 r2 = *(const uint2*)(mh_in + (c4.y & 0xFFFFu) * 64u + co);
    uint2 r3 = *(const uint2*)(mh_in + (c4.y >> 16) * 64u + co);
    uint2 r4 = *(const uint2*)(mh_in + (c4.z & 0xFFFFu) * 64u + co);
    uint2 r5 = *(const uint2*)(mh_in + (c4.z >> 16) * 64u + co);
    uint2 r6 = *(const uint2*)(mh_in + (c4.w & 0xFFFFu) * 64u + co);
    uint2 r7 = *(const uint2*)(mh_in + (c4.w >> 16) * 64u + co);
    for (p += 8; p < se.y; p += 8) {
        uint2 n0 = *(const uint2*)(mh_in + (c4n.x & 0xFFFFu) * 64u + co);
        uint2 n1 = *(const uint2*)(mh_in + (c4n.x >> 16) * 64u + co);
        uint2 n2 = *(const uint2*)(mh_in + (c4n.y & 0xFFFFu) * 64u + co);
        uint2 n3 = *(const uint2*)(mh_in + (c4n.y >> 16) * 64u + co);
        uint2 n4 = *(const uint2*)(mh_in + (c4n.z & 0xFFFFu) * 64u + co);
        uint2 n5 = *(const uint2*)(mh_in + (c4n.z >> 16) * 64u + co);
        uint2 n6 = *(const uint2*)(mh_in + (c4n.w & 0xFFFFu) * 64u + co);
        uint2 n7 = *(const uint2*)(mh_in + (c4n.w >> 16) * 64u + co);
        c4n = *(const uint4*)(csr + p + 8);        // next-next indices
        mnA = pk_min_u16(mnA, r0.x); mnB = pk_min_u16(mnB, r0.y);
        mnC = pk_min_u16(mnC, r1.x); mnD = pk_min_u16(mnD, r1.y);
        mnA = pk_min_u16(mnA, r2.x); mnB = pk_min_u16(mnB, r2.y);
        mnC = pk_min_u16(mnC, r3.x); mnD = pk_min_u16(mnD, r3.y);
        mnA = pk_min_u16(mnA, r4.x); mnB = pk_min_u16(mnB, r4.y);
        mnC = pk_min_u16(mnC, r5.x); mnD = pk_min_u16(mnD, r5.y);
        mnA = pk_min_u16(mnA, r6.x); mnB = pk_min_u16(mnB, r6.y);
        mnC = pk_min_u16(mnC, r7.x); mnD = pk_min_u16(mnD, r7.y);
        r0 = n0; r1 = n1; r2 = n2; r3 = n3;
        r4 = n4; r5 = n5; r6 = n6; r7 = n7;
    }
    mnA = pk_min_u16(mnA, r0.x); mnB = pk_min_u16(mnB, r0.y);
    mnC = pk_min_u16(mnC, r1.x); mnD = pk_min_u16(mnD, r1.y);
    mnA = pk_min_u16(mnA, r2.x); mnB = pk_min_u16(mnB, r2.y);
    mnC = pk_min_u16(mnC, r3.x); mnD = pk_min_u16(mnD, r3.y);
    mnA = pk_min_u16(mnA, r4.x); mnB = pk_min_u16(mnB, r4.y);
    mnC = pk_min_u16(mnC, r5.x); mnD = pk_min_u16(mnD, r5.y);
    mnA = pk_min_u16(mnA, r6.x); mnB = pk_min_u16(mnB, r6.y);
    mnC = pk_min_u16(mnC, r7.x); mnD = pk_min_u16(mnD, r7.y);
    uint m0 = pk_min_u16(mnA, mnC);
    uint m1 = pk_min_u16(mnB, mnD);
    if (out_p) {
        uint2 w = {m0, m1};
        *(uint2*)(out_p + (size_t)node * 64 + co) = w;
    } else {
        float4 w;
        w.x = __uint_as_float((m0 & 0xFFFFu) << 16);
        w.y = __uint_as_float(m0 & 0xFFFF0000u);
        w.z = __uint_as_float((m1 & 0xFFFFu) << 16);
        w.w = __uint_as_float(m1 & 0xFFFF0000u);
        *(float4*)(out_f + (size_t)node * NPERM + 2u * co) = w;
    }
}

// ========== hll: 16 lanes/node, uint/lane, csr prefetch (4 chains/wave already) ==========

__device__ __forceinline__ void hll_body(int node, uint q, const int2* __restrict__ off2,
                                         const ushort* __restrict__ csr,
                                         const uint* __restrict__ hll_in,
                                         uint* __restrict__ out_p, float* __restrict__ out_f,
                                         float* __restrict__ cards, int kcol) {
    int2 se = off2[node];
    uint m0 = 0, m1 = 0, m2 = 0, m3 = 0;
#define HLL_ACC(vv) do { uint _v = (vv); \
        m0 = max(m0, _v & 0xFFu); m1 = max(m1, (_v >> 8) & 0xFFu); \
        m2 = max(m2, (_v >> 16) & 0xFFu); m3 = max(m3, _v >> 24); } while (0)
    int p = se.x;
    uint4 c4 = *(const uint4*)(csr + p);
    for (; p < se.y; ) {
        int pn = p + 8;
        uint4 c4n = *(const uint4*)(csr + pn);
        uint j0 = c4.x & 0xFFFFu, j1 = c4.x >> 16;
        uint j2 = c4.y & 0xFFFFu, j3 = c4.y >> 16;
        uint j4 = c4.z & 0xFFFFu, j5 = c4.z >> 16;
        uint j6 = c4.w & 0xFFFFu, j7 = c4.w >> 16;
        uint a0 = hll_in[j0 * 16u + q];
        uint a1 = hll_in[j1 * 16u + q];
        uint a2 = hll_in[j2 * 16u + q];
        uint a3 = hll_in[j3 * 16u + q];
        uint a4 = hll_in[j4 * 16u + q];
        uint a5 = hll_in[j5 * 16u + q];
        uint a6 = hll_in[j6 * 16u + q];
        uint a7 = hll_in[j7 * 16u + q];
        HLL_ACC(a0); HLL_ACC(a1); HLL_ACC(a2); HLL_ACC(a3);
        HLL_ACC(a4); HLL_ACC(a5); HLL_ACC(a6); HLL_ACC(a7);
        c4 = c4n; p = pn;
    }
#undef HLL_ACC
    if (out_p) out_p[(size_t)node * 16 + q] = m0 | (m1 << 8) | (m2 << 16) | (m3 << 24);
    if (out_f) {
        float4 w = {(float)m0, (float)m1, (float)m2, (float)m3};
        *(float4*)(out_f + (size_t)node * HLLM + 4 * q) = w;
    }
    float v = exp2f(-(float)m0) + exp2f(-(float)m1) + exp2f(-(float)m2) + exp2f(-(float)m3);
    v += __shfl_xor(v, 1); v += __shfl_xor(v, 2);
    v += __shfl_xor(v, 4); v += __shfl_xor(v, 8);
    if (q == 0) {
        const float alphamm = (float)(0.7213 / (1.0 + 1.079 / 64.0) * 64.0 * 64.0);
        cards[(size_t)node * 2 + kcol] = alphamm / v;
    }
}

// ========== agg: 2 nodes/wave, uint/lane, SOFTWARE-PIPELINED row loads ==========

__device__ __forceinline__ void agg_body(int node, uint c2, const int2* __restrict__ off2,
                                         const ushort* __restrict__ csr,
                                         const uint* __restrict__ hWs32,
                                         const float* __restrict__ dis,
                                         const float* __restrict__ b,
                                         const float* __restrict__ h_in,
                                         float* __restrict__ h_out) {
    int2 se = off2[node];
    float ax0 = 0.f, ay0 = 0.f, ax1 = 0.f, ay1 = 0.f;
    int p = se.x;
    uint4 c4 = *(const uint4*)(csr + p);
    uint4 c4n = *(const uint4*)(csr + p + 8);
    uint r0 = hWs32[(c4.x & 0xFFFFu) * 32u + c2];
    uint r1 = hWs32[(c4.x >> 16) * 32u + c2];
    uint r2 = hWs32[(c4.y & 0xFFFFu) * 32u + c2];
    uint r3 = hWs32[(c4.y >> 16) * 32u + c2];
    uint r4 = hWs32[(c4.z & 0xFFFFu) * 32u + c2];
    uint r5 = hWs32[(c4.z >> 16) * 32u + c2];
    uint r6 = hWs32[(c4.w & 0xFFFFu) * 32u + c2];
    uint r7 = hWs32[(c4.w >> 16) * 32u + c2];
#define AGG_RED() do { \
        ax0 += __uint_as_float(r0 << 16) + __uint_as_float(r1 << 16) \
             + __uint_as_float(r2 << 16) + __uint_as_float(r3 << 16); \
        ay0 += __uint_as_float(r0 & 0xFFFF0000u) + __uint_as_float(r1 & 0xFFFF0000u) \
             + __uint_as_float(r2 & 0xFFFF0000u) + __uint_as_float(r3 & 0xFFFF0000u); \
        ax1 += __uint_as_float(r4 << 16) + __uint_as_float(r5 << 16) \
             + __uint_as_float(r6 << 16) + __uint_as_float(r7 << 16); \
        ay1 += __uint_as_float(r4 & 0xFFFF0000u) + __uint_as_float(r5 & 0xFFFF0000u) \
             + __uint_as_float(r6 & 0xFFFF0000u) + __uint_as_float(r7 & 0xFFFF0000u); } while (0)
    for (p += 8; p < se.y; p += 8) {
        uint n0 = hWs32[(c4n.x & 0xFFFFu) * 32u + c2];
        uint n1 = hWs32[(c4n.x >> 16) * 32u + c2];
        uint n2 = hWs32[(c4n.y & 0xFFFFu) * 32u + c2];
        uint n3 = hWs32[(c4n.y >> 16) * 32u + c2];
        uint n4 = hWs32[(c4n.z & 0xFFFFu) * 32u + c2];
        uint n5 = hWs32[(c4n.z >> 16) * 32u + c2];
        uint n6 = hWs32[(c4n.w & 0xFFFFu) * 32u + c2];
        uint n7 = hWs32[(c4n.w >> 16) * 32u + c2];
        c4n = *(const uint4*)(csr + p + 8);
        AGG_RED();
        r0 = n0; r1 = n1; r2 = n2; r3 = n3;
        r4 = n4; r5 = n5; r6 = n6; r7 = n7;
    }
    AGG_RED();
#undef AGG_RED
    float ax = ax0 + ax1, ay = ay0 + ay1;
    uint ch = 2u * c2;
    size_t idx = (size_t)node * HID + ch;
    float2 hi = *(const float2*)(h_in + idx);
    float2 bb = *(const float2*)(b + ch);
    float d = dis[node];
    float2 o;
    o.x = hi.x + bb.x + d * ax;
    o.y = hi.y + bb.y + d * ay;
    *(float2*)(h_out + idx) = o;
}

__device__ __forceinline__ void convmm_body(int row, int c0, const float* __restrict__ h,
                                            const float* __restrict__ Ws,
                                            const float* __restrict__ dis,
                                            ushort* __restrict__ hWs) {
    float acc[16] = {0.f, 0.f, 0.f, 0.f, 0.f, 0.f, 0.f, 0.f,
                     0.f, 0.f, 0.f, 0.f, 0.f, 0.f, 0.f, 0.f};
    const float4* hr = (const float4*)(h + (size_t)row * HID);
    for (int k4 = 0; k4 < HID / 4; ++k4) {
        float4 hv = hr[k4];
        const float* wr = Ws + (k4 * 4) * HID + c0;
#pragma unroll
        for (int j = 0; j < 16; ++j) acc[j] = fmaf(hv.x, wr[j], acc[j]);
#pragma unroll
        for (int j = 0; j < 16; ++j) acc[j] = fmaf(hv.y, wr[HID + j], acc[j]);
#pragma unroll
        for (int j = 0; j < 16; ++j) acc[j] = fmaf(hv.z, wr[2 * HID + j], acc[j]);
#pragma unroll
        for (int j = 0; j < 16; ++j) acc[j] = fmaf(hv.w, wr[3 * HID + j], acc[j]);
    }
    float d = dis[row];
    ushort* o = hWs + (size_t)row * HID + c0;
#pragma unroll
    for (int j = 0; j < 16; ++j) {
        __hip_bfloat16 t = __float2bfloat16(d * acc[j]);
        o[j] = *(ushort*)&t;
    }
}

// ================= k_front: scatter | pack mh | pack hll | dummy init =================

__global__ void __launch_bounds__(256) k_front(const int* __restrict__ src,
                       const int* __restrict__ dst, int* __restrict__ gcur,
                       uint* __restrict__ ebuf,
                       const int* __restrict__ mh, uint* __restrict__ mhp,
                       uint* __restrict__ mhA,
                       const int* __restrict__ hll, uint* __restrict__ hp,
                       uint* __restrict__ hllA) {
    __shared__ uint ecache[EDGES_PER_BLK];
    __shared__ int cnt[NBUCK];
    __shared__ int cur[NBUCK];
    int b = blockIdx.x;
    int t = threadIdx.x;
    if (b < SCAT_BLOCKS) {
        for (int i = t; i < NBUCK; i += 256) cnt[i] = 0;
        __syncthreads();
        int e0 = b * EDGES_PER_BLK;
        for (int i = t; i < EDGES_PER_BLK; i += 256) {
            int d = dst[e0 + i];
            int s = src[e0 + i];
            ecache[i] = ((uint)s << 16) | (uint)d;   // both < 65536
            atomicAdd(&cnt[d >> BSHIFT], 1);
        }
        __syncthreads();
        for (int bb = t; bb < NBUCK; bb += 256)
            cur[bb] = bb * CAPB + atomicAdd(&gcur[bb], cnt[bb]);
        __syncthreads();
        for (int i = t; i < EDGES_PER_BLK; i += 256) {
            uint en = ecache[i];
            uint d = en & 0xFFFFu;
            int p = atomicAdd(&cur[d >> BSHIFT], 1);
            ebuf[p] = ((en >> 16) << BSHIFT) | (d & (BNODES - 1));
        }
    } else if (b < SCAT_BLOCKS + PACKMH_BLOCKS) {
        int i = (b - SCAT_BLOCKS) * 256 + t;
        int2 v = ((const int2*)mh)[i];
        uint u0 = __float_as_uint((float)v.x) >> 16;
        uint u1 = __float_as_uint((float)v.y) >> 16;
        mhp[i] = u0 | (u1 << 16);
    } else if (b < SCAT_BLOCKS + PACKMH_BLOCKS + HLL_BLOCKS) {
        int i = (b - SCAT_BLOCKS - PACKMH_BLOCKS) * 256 + t;
        int4 v = ((const int4*)hll)[i];
        hp[i] = (uint)v.x | ((uint)v.y << 8) | ((uint)v.z << 16) | ((uint)v.w << 24);
    } else {
        if (t < 64) {
            mhp[(size_t)DUMMY * 64 + t] = 0xFFFFFFFFu;
            mhA[(size_t)DUMMY * 64 + t] = 0xFFFFFFFFu;
        } else if (t < 80) {
            hp[(size_t)DUMMY * 16 + (t - 64)] = 0u;
        } else if (t < 96) {
            hllA[(size_t)DUMMY * 16 + (t - 80)] = 0u;
        }
    }
}

// ================= k_fat1: csr | encoder =================

__global__ void __launch_bounds__(256) k_fat1(const uint* __restrict__ ebuf,
                      const int* __restrict__ gcur, int* __restrict__ pcur,
                      int2* __restrict__ off2, float* __restrict__ dis,
                      ushort* __restrict__ csr,
                      const float* __restrict__ x, const float* __restrict__ W_enc,
                      const float* __restrict__ b_enc, float* __restrict__ h) {
    __shared__ uint smem[SLICE_CAP + BNODES + 256 + 1];   // ~35.8 KB
    int b = blockIdx.x;
    int t = threadIdx.x;
    if (b < NBUCK) {
        uint* slice = smem;
        int* lcur = (int*)(smem + SLICE_CAP);
        int* ssum = (int*)(smem + SLICE_CAP + BNODES);
        int* sbase = (int*)(smem + SLICE_CAP + BNODES + 256);
        int lo = b << BSHIFT;
        int nbkt = min(BNODES, N_NODES - lo);
        int ebase = b * CAPB;
        int ecnt = gcur[b];
        lcur[t] = 0;
        __syncthreads();
        for (int i = t; i < ecnt; i += 256)
            atomicAdd(&lcur[ebuf[ebase + i] & (BNODES - 1)], 1);
        __syncthreads();
        int a0 = lcur[t];                      // in-degree (excl self)
        int plen = (t < nbkt) ? ((a0 + 8) & ~7) : 0;   // padded length incl self
        ssum[t] = plen;
        __syncthreads();
        for (int off = 1; off < 256; off <<= 1) {
            int u = (t >= off) ? ssum[t - off] : 0;
            __syncthreads();
            ssum[t] += u;
            __syncthreads();
        }
        int ppre = ssum[t] - plen;
        if (t == 255) sbase[0] = atomicAdd(pcur, ssum[255]);
        __syncthreads();
        int base = sbase[0];
        if (t < nbkt) {
            slice[ppre] = (uint)(lo + t);      // self-loop first
            lcur[t] = ppre + 1;
            off2[lo + t] = make_int2(base + ppre, base + ppre + plen);
            dis[lo + t] = rsqrtf((float)(a0 + 1));
        }
        __syncthreads();
        for (int i = t; i < ecnt; i += 256) {
            uint en = ebuf[ebase + i];
            int p = atomicAdd(&lcur[en & (BNODES - 1)], 1);
            slice[p] = en >> BSHIFT;
        }
        __syncthreads();
        if (t < nbkt)
            for (int i = lcur[t]; i < ppre + plen; ++i) slice[i] = DUMMY;
        __syncthreads();
        int total = ssum[255];
        for (int i = t; i < total; i += 256) csr[base + i] = (ushort)slice[i];
    } else {
        float* Ws = (float*)smem;
        for (int idx = t; idx < FDIM * HID; idx += 256) Ws[idx] = W_enc[idx];
        __syncthreads();
        int row = (b - NBUCK) * 64 + (t >> 2);
        int c0 = (t & 3) * 16;
        if (row >= N_NODES) return;
        float acc[16];
#pragma unroll
        for (int j = 0; j < 16; ++j) acc[j] = b_enc[c0 + j];
        const float4* xr = (const float4*)(x + (size_t)row * FDIM);
        for (int k4 = 0; k4 < FDIM / 4; ++k4) {
            float4 xv = xr[k4];
            const float* wr = Ws + (k4 * 4) * HID + c0;
#pragma unroll
            for (int j = 0; j < 16; ++j) acc[j] = fmaf(xv.x, wr[j], acc[j]);
#pragma unroll
            for (int j = 0; j < 16; ++j) acc[j] = fmaf(xv.y, wr[HID + j], acc[j]);
#pragma unroll
            for (int j = 0; j < 16; ++j) acc[j] = fmaf(xv.z, wr[2 * HID + j], acc[j]);
#pragma unroll
            for (int j = 0; j < 16; ++j) acc[j] = fmaf(xv.w, wr[3 * HID + j], acc[j]);
        }
        float* hr = h + (size_t)row * HID + c0;
#pragma unroll
        for (int j = 0; j < 16; ++j) hr[j] = acc[j];
    }
}

// ================= D1: mh0 | hll0 | conv0 (conv uses LDS W tile) =================

__global__ void __launch_bounds__(256, 8) k_hopA(const int2* __restrict__ off2,
                    const ushort* __restrict__ csr,
                    const uint* __restrict__ mh_in, uint* __restrict__ mh_out_p,
                    const uint* __restrict__ hll_in, uint* __restrict__ hll_out_p,
                    float* __restrict__ cards,
                    const float* __restrict__ h, const float* __restrict__ W,
                    const float* __restrict__ dis, ushort* __restrict__ hWs) {
    __shared__ float Ws[HID * HID];   // 16 KB; 8 blocks/CU still fits 128 KB
    int blk = blockIdx.x;
    int t = threadIdx.x;
    if (blk < MH2_BLOCKS) {
        int node = blk * 8 + (t >> 6) * 2 + ((t >> 5) & 1);
        mh_body(node, t & 31, off2, csr, mh_in, mh_out_p, nullptr);
    } else if (blk < MH2_BLOCKS + HLL_BLOCKS) {
        int node = (blk - MH2_BLOCKS) * 16 + (t >> 4);
        hll_body(node, t & 15, off2, csr, hll_in, hll_out_p, nullptr, cards, 0);
    } else {
        for (int i = t; i < HID * HID; i += 256) Ws[i] = W[i];
        __syncthreads();
        int row = (blk - MH2_BLOCKS - HLL_BLOCKS) * 64 + (t >> 2);
        int c0 = (t & 3) * 16;
        if (row > N_NODES) return;
        if (row == N_NODES) {           // dummy zero row
            ushort* o = hWs + (size_t)row * HID + c0;
#pragma unroll
            for (int j = 0; j < 16; ++j) o[j] = 0;
            return;
        }
        convmm_body(row, c0, h, Ws, dis, hWs);
    }
}

// ================= D2: mh1 | agg0 | hll1 =================

__global__ void __launch_bounds__(256, 8) k_hopB(const int2* __restrict__ off2,
                    const ushort* __restrict__ csr,
                    const uint* __restrict__ mh_in, float* __restrict__ mh_out_f,
                    const uint* __restrict__ hWs32, const float* __restrict__ b0,
                    float* __restrict__ h_cur,
                    const uint* __restrict__ hll_in, float* __restrict__ hll_out_f,
                    float* __restrict__ cards, const float* __restrict__ dis) {
    int blk = blockIdx.x;
    int t = threadIdx.x;
    if (blk < MH2_BLOCKS) {
        int node = blk * 8 + (t >> 6) * 2 + ((t >> 5) & 1);
        mh_body(node, t & 31, off2, csr, mh_in, nullptr, mh_out_f);
    } else if (blk < MH2_BLOCKS + AGG2_BLOCKS) {
        int node = (blk - MH2_BLOCKS) * 8 + (t >> 6) * 2 + ((t >> 5) & 1);
        agg_body(node, t & 31, off2, csr, hWs32, dis, b0, h_cur, h_cur);
    } else {
        int node = (blk - MH2_BLOCKS - AGG2_BLOCKS) * 16 + (t >> 4);
        hll_body(node, t & 15, off2, csr, hll_in, nullptr, hll_out_f, cards, 1);
    }
}

// ================= D3: conv1 =================

__global__ void __launch_bounds__(256) k_conv(const float* __restrict__ h,
                         const float* __restrict__ W, const float* __restrict__ dis,
                         ushort* __restrict__ hWs) {
    __shared__ float Ws[HID * HID];
    for (int i = threadIdx.x; i < HID * HID; i += 256) Ws[i] = W[i];
    __syncthreads();
    int row = blockIdx.x * 64 + (threadIdx.x >> 2);
    int c0 = (threadIdx.x & 3) * 16;
    if (row > N_NODES) return;
    if (row == N_NODES) {
        ushort* o = hWs + (size_t)row * HID + c0;
#pragma unroll
        for (int j = 0; j < 16; ++j) o[j] = 0;
        return;
    }
    convmm_body(row, c0, h, Ws, dis, hWs);
}

// ================= D4: agg1 -> out_h =================

__global__ void __launch_bounds__(256, 8) k_agg(const int2* __restrict__ off2,
                      const ushort* __restrict__ csr, const uint* __restrict__ hWs32,
                      const float* __restrict__ dis, const float* __restrict__ b,
                      const float* __restrict__ h_in, float* __restrict__ h_out) {
    int t = threadIdx.x;
    int node = blockIdx.x * 8 + (t >> 6) * 2 + ((t >> 5) & 1);
    agg_body(node, t & 31, off2, csr, hWs32, dis, b, h_in, h_out);
}

// ---------------- driver ----------------

static inline char* align256(char* p) {
    return (char*)(((uintptr_t)p + 255) & ~(uintptr_t)255);
}

extern "C" void kernel_launch(void* const* d_in, const int* in_sizes, int n_in,
                              void* d_out, int out_size, void* d_ws, size_t ws_size,
                              hipStream_t stream) {
    const float* x       = (const float*)d_in[0];
    const int*   ei      = (const int*)d_in[1];
    const int*   mh0     = (const int*)d_in[2];
    const int*   hll0    = (const int*)d_in[3];
    const float* W_enc   = (const float*)d_in[4];
    const float* b_enc   = (const float*)d_in[5];
    const float* W_convs = (const float*)d_in[6];
    const float* b_convs = (const float*)d_in[7];

    float* out       = (float*)d_out;
    float* out_h     = out;
    float* out_cards = out + (size_t)N_NODES * HID;
    float* out_mh    = out_cards + (size_t)N_NODES * 2;
    float* out_hll   = out_mh + (size_t)N_NODES * NPERM;

    char* w = (char*)d_ws;
    int*   gcur    = (int*)w;   w += (size_t)NBUCK * 4;
    int*   pcur    = (int*)w;   w = align256(w + 4);
    int2*  off2    = (int2*)w;  w = align256(w + (size_t)N_NODES * 8);
    float* dis     = (float*)w; w = align256(w + (size_t)N_NODES * 4);
    ushort* csr    = (ushort*)w; w = align256(w + (size_t)(N_EDGES + 8 * N_NODES + 32) * 2);
    uint*  mhp0    = (uint*)w;  w = align256(w + (size_t)(N_NODES + 1) * 64 * 4);
    uint*  mhA     = (uint*)w;  w = align256(w + (size_t)(N_NODES + 1) * 64 * 4);
    uint*  hp0     = (uint*)w;  w = align256(w + (size_t)(N_NODES + 1) * 16 * 4);
    uint*  hllA    = (uint*)w;  w = align256(w + (size_t)(N_NODES + 1) * 16 * 4);
    float* h_cur   = (float*)w; w = align256(w + (size_t)N_NODES * HID * 4);
    ushort* hWs    = (ushort*)w; w = align256(w + (size_t)(N_NODES + 1) * HID * 2);
    uint*  ebuf    = mhA;  // build-phase alias (196*6144 uints = 4.8MB < 12.8MB extent);
                           // dummy row at 12.8MB offset untouched by ebuf

    const int* src = ei;
    const int* dst = ei + N_EDGES;

    // zero gcur (+pcur, adjacent) -> fixed bucket bases added in-kernel
    hipMemsetAsync(gcur, 0, (size_t)(NBUCK + 1) * 4, stream);
    // F1: scatter | pack mh | pack hll | dummy init
    k_front<<<SCAT_BLOCKS + PACKMH_BLOCKS + HLL_BLOCKS + 1, 256, 0, stream>>>(
        src, dst, gcur, ebuf, mh0, mhp0, mhA, hll0, hp0, hllA);
    // F2: csr | encoder
    k_fat1<<<NBUCK + CONV_BLOCKS, 256, 0, stream>>>(
        ebuf, gcur, pcur, off2, dis, csr, x, W_enc, b_enc, h_cur);

    // D1: mh0 | hll0 | conv0
    k_hopA<<<MH2_BLOCKS + HLL_BLOCKS + CONV_BLOCKS + 1, 256, 0, stream>>>(
        off2, csr, mhp0, mhA, hp0, hllA, out_cards, h_cur, W_convs, dis, hWs);
    // D2: mh1 | agg0 | hll1
    k_hopB<<<MH2_BLOCKS + AGG2_BLOCKS + HLL_BLOCKS, 256, 0, stream>>>(
        off2, csr, mhA, out_mh, (const uint*)hWs, b_convs, h_cur, hllA, out_hll, out_cards, dis);
    // D3: conv1
    k_conv<<<CONV_BLOCKS + 1, 256, 0, stream>>>(h_cur, W_convs + HID * HID, dis, hWs);
    // D4: agg1 -> out_h
    k_agg<<<AGG2_BLOCKS, 256, 0, stream>>>(off2, csr, (const uint*)hWs, dis, b_convs + HID, h_cur, out_h);
}